// Round 14
// baseline (723.776 us; speedup 1.0000x reference)
//
#include <hip/hip_runtime.h>

#define NTOK 16384
#define HDIM 2048
#define HD4  512
#define NG   4
#define EPG  16
#define NE   64
#define KSPLIT 4

// ---------------------------------------------------------------------------
// Kernel 1 (v7): fused  confp = partial( gelu(x@Wc1+bc1) . Wc2 )
// Same verified v6 skeleton (grid (256,2), 512 thr, dbuf LDS, 1 barrier/tile).
// Changes vs v6:
//  (A) inner loop = explicit member FMAs (no av[]/bv[] unpack movs, which
//      were ~30% of all VALU issue in r13).
//  (B) h is never materialized: epilogue GELUs in-register, dots with Wc2,
//      butterfly-reduces across the wave, writes confp[half][row].
// acc order per element = sequential k=0..2047 (selections unchanged).
// ---------------------------------------------------------------------------
__global__ __launch_bounds__(512) void gemm_conf_kernel(
    const float* __restrict__ x, const float* __restrict__ Wc1,
    const float* __restrict__ bc1, const float* __restrict__ Wc2,
    float* __restrict__ confp)
{
    __shared__ float Bs[2][16][260];   // [buf][kk][col in half], pad 4
    __shared__ float As[2][16][68];    // [buf][kk][row]
    const int tid  = threadIdx.x;      // 0..511
    const int bm   = blockIdx.x;       // 0..255 : rows bm*64..+63
    const int half = blockIdx.y;       // 0..1   : cols half*256..+255
    const int w    = tid >> 6;         // 0..7
    const int lane = tid & 63;
    const int rbase = w * 8;
    const int cb   = lane * 4;         // col-in-half base

    const bool aStager = (tid < 256);
    const int srow = (tid & 255) >> 2; // 0..63
    const int skq  = tid & 3;          // float4 at k = skq*4
    const float* xsrc = x + (size_t)(bm * 64 + srow) * HDIM + skq * 4;

    const int kb = tid & 15, sb = tid >> 4;   // sb 0..31, 8 cols each
    const float* wsrc = Wc1 + (size_t)kb * HD4 + half * 256 + sb * 8;

    float acc[8][4];
#pragma unroll
    for (int r = 0; r < 8; ++r)
#pragma unroll
        for (int j = 0; j < 4; ++j) acc[r][j] = 0.0f;

    float4 a0r = make_float4(0.f, 0.f, 0.f, 0.f);
    if (aStager) a0r = *(const float4*)(xsrc);
    float4 b0r = *(const float4*)(wsrc);
    float4 b1r = *(const float4*)(wsrc + 4);

    int cur = 0;
    const int NT = HDIM / 16;          // 128 tiles

    for (int t = 0; t < NT; ++t) {
        if (aStager) {
            const int kk = skq * 4;
            As[cur][kk + 0][srow] = a0r.x;
            As[cur][kk + 1][srow] = a0r.y;
            As[cur][kk + 2][srow] = a0r.z;
            As[cur][kk + 3][srow] = a0r.w;
        }
        *(float4*)&Bs[cur][kb][sb * 8]     = b0r;
        *(float4*)&Bs[cur][kb][sb * 8 + 4] = b1r;
        if (t + 1 < NT) {
            if (aStager) a0r = *(const float4*)(xsrc + (t + 1) * 16);
            const float* wn = wsrc + (size_t)(t + 1) * 16 * HD4;
            b0r = *(const float4*)(wn);
            b1r = *(const float4*)(wn + 4);
        }
        __syncthreads();

#pragma unroll
        for (int kk = 0; kk < 16; ++kk) {
            float4 av0 = *(const float4*)&As[cur][kk][rbase];
            float4 av1 = *(const float4*)&As[cur][kk][rbase + 4];
            float4 bv  = *(const float4*)&Bs[cur][kk][cb];
#define ROWFMA(R, AV)                              \
            acc[R][0] = fmaf(AV, bv.x, acc[R][0]); \
            acc[R][1] = fmaf(AV, bv.y, acc[R][1]); \
            acc[R][2] = fmaf(AV, bv.z, acc[R][2]); \
            acc[R][3] = fmaf(AV, bv.w, acc[R][3]);
            ROWFMA(0, av0.x) ROWFMA(1, av0.y) ROWFMA(2, av0.z) ROWFMA(3, av0.w)
            ROWFMA(4, av1.x) ROWFMA(5, av1.y) ROWFMA(6, av1.z) ROWFMA(7, av1.w)
#undef ROWFMA
        }
        cur ^= 1;
        // single barrier/tile: next iter writes the OTHER buffer (v6-verified)
    }

    // epilogue: bias + exact GELU + dot with Wc2 + wave butterfly reduce
    const int gcol = half * 256 + cb;
    float4 bq = *(const float4*)(bc1 + gcol);
    float4 wq = *(const float4*)(Wc2 + gcol);
    float p[8];
#pragma unroll
    for (int r = 0; r < 8; ++r) {
        float v0 = acc[r][0] + bq.x;
        float v1 = acc[r][1] + bq.y;
        float v2 = acc[r][2] + bq.z;
        float v3 = acc[r][3] + bq.w;
        float o0 = 0.5f * v0 * (1.0f + erff(v0 * 0.70710678118654752440f));
        float o1 = 0.5f * v1 * (1.0f + erff(v1 * 0.70710678118654752440f));
        float o2 = 0.5f * v2 * (1.0f + erff(v2 * 0.70710678118654752440f));
        float o3 = 0.5f * v3 * (1.0f + erff(v3 * 0.70710678118654752440f));
        float s = o0 * wq.x;
        s = fmaf(o1, wq.y, s);
        s = fmaf(o2, wq.z, s);
        s = fmaf(o3, wq.w, s);
        p[r] = s;
    }
#pragma unroll
    for (int m = 32; m; m >>= 1) {
#pragma unroll
        for (int r = 0; r < 8; ++r) p[r] += __shfl_xor(p[r], m, 64);
    }
    if (lane == 0) {
#pragma unroll
        for (int r = 0; r < 8; ++r)
            confp[(size_t)half * NTOK + bm * 64 + rbase + r] = p[r];
    }
}

// ---------------------------------------------------------------------------
// Kernel 3: El partials = x @ We_flat over K-chunk ks (K-split=4)
// ---------------------------------------------------------------------------
__global__ __launch_bounds__(256) void gemm_experts_kernel(
    const float* __restrict__ x, const float* __restrict__ We,
    float* __restrict__ Elp)
{
    __shared__ float As[16][68];
    __shared__ float Bs[16][68];
    const int tid = threadIdx.x;
    const int bm = blockIdx.x;      // 0..255
    const int ks = blockIdx.y;      // 0..3 K-chunk
    const int tr = tid >> 4, tc = tid & 15;

    float acc[4][4];
#pragma unroll
    for (int i = 0; i < 4; ++i)
#pragma unroll
        for (int j = 0; j < 4; ++j) acc[i][j] = 0.0f;

    const float* xb = x + (size_t)bm * 64 * HDIM;
    const int arow = tid >> 2, ak4 = tid & 3;
    const int bkk = tid >> 4;
    const int bgrp = (tid >> 2) & 3;
    const int be4 = tid & 3;

    const int kbeg = ks * (HDIM / KSPLIT);
    const int kend = kbeg + (HDIM / KSPLIT);
    for (int k0 = kbeg; k0 < kend; k0 += 16) {
        float4 va = *(const float4*)(xb + (size_t)arow * HDIM + k0 + ak4 * 4);
        As[ak4 * 4 + 0][arow] = va.x;
        As[ak4 * 4 + 1][arow] = va.y;
        As[ak4 * 4 + 2][arow] = va.z;
        As[ak4 * 4 + 3][arow] = va.w;
        *(float4*)&Bs[bkk][bgrp * 16 + be4 * 4] =
            *(const float4*)(We + (size_t)bgrp * HDIM * EPG
                             + (size_t)(k0 + bkk) * EPG + be4 * 4);
        __syncthreads();

        float acc_t[4][4];
#pragma unroll
        for (int i = 0; i < 4; ++i)
#pragma unroll
            for (int j = 0; j < 4; ++j) acc_t[i][j] = 0.0f;
#pragma unroll
        for (int k = 0; k < 16; ++k) {
            float av[4], bv[4];
            *(float4*)av = *(const float4*)&As[k][tr * 4];
            *(float4*)bv = *(const float4*)&Bs[k][tc * 4];
#pragma unroll
            for (int i = 0; i < 4; ++i)
#pragma unroll
                for (int j = 0; j < 4; ++j)
                    acc_t[i][j] = fmaf(av[i], bv[j], acc_t[i][j]);
        }
#pragma unroll
        for (int i = 0; i < 4; ++i)
#pragma unroll
            for (int j = 0; j < 4; ++j) acc[i][j] += acc_t[i][j];
        __syncthreads();
    }
#pragma unroll
    for (int i = 0; i < 4; ++i) {
        float o[4] = {acc[i][0], acc[i][1], acc[i][2], acc[i][3]};
        *(float4*)(Elp + ((size_t)ks * NTOK + bm * 64 + tr * 4 + i) * NE + tc * 4)
            = *(float4*)o;
    }
}

// ---------------------------------------------------------------------------
// Kernel 3b: El = sum over K-chunks (fixed order, deterministic)
// ---------------------------------------------------------------------------
__global__ __launch_bounds__(256) void reduce_el_kernel(
    const float* __restrict__ Elp, float* __restrict__ El)
{
    const size_t i = ((size_t)blockIdx.x * 256 + threadIdx.x) * 4;
    float4 a = *(const float4*)(Elp + i);
    float4 b = *(const float4*)(Elp + (size_t)1 * NTOK * NE + i);
    float4 c = *(const float4*)(Elp + (size_t)2 * NTOK * NE + i);
    float4 d = *(const float4*)(Elp + (size_t)3 * NTOK * NE + i);
    float4 r;
    r.x = ((a.x + b.x) + c.x) + d.x;
    r.y = ((a.y + b.y) + c.y) + d.y;
    r.z = ((a.z + b.z) + c.z) + d.z;
    r.w = ((a.w + b.w) + c.w) + d.w;
    *(float4*)(El + i) = r;
}

// ---------------------------------------------------------------------------
// Kernel 4: Gl = x @ Wg, one wave per row
// ---------------------------------------------------------------------------
__global__ __launch_bounds__(256) void gemv_gates_kernel(
    const float* __restrict__ x, const float* __restrict__ Wg,
    float* __restrict__ Gl)
{
    const int wv = threadIdx.x >> 6, lane = threadIdx.x & 63;
    const int n = blockIdx.x * 4 + wv;
    const float* xr = x + (size_t)n * HDIM;
    float a0 = 0, a1 = 0, a2 = 0, a3 = 0;
#pragma unroll
    for (int t = 0; t < 8; ++t) {
        const int k = t * 256 + lane * 4;
        float4 xv = *(const float4*)(xr + k);
        float4 w0 = *(const float4*)(Wg + (size_t)k * NG);
        float4 w1 = *(const float4*)(Wg + (size_t)k * NG + 4);
        float4 w2 = *(const float4*)(Wg + (size_t)k * NG + 8);
        float4 w3 = *(const float4*)(Wg + (size_t)k * NG + 12);
        a0 = fmaf(xv.x, w0.x, a0); a0 = fmaf(xv.y, w1.x, a0);
        a0 = fmaf(xv.z, w2.x, a0); a0 = fmaf(xv.w, w3.x, a0);
        a1 = fmaf(xv.x, w0.y, a1); a1 = fmaf(xv.y, w1.y, a1);
        a1 = fmaf(xv.z, w2.y, a1); a1 = fmaf(xv.w, w3.y, a1);
        a2 = fmaf(xv.x, w0.z, a2); a2 = fmaf(xv.y, w1.z, a2);
        a2 = fmaf(xv.z, w2.z, a2); a2 = fmaf(xv.w, w3.z, a2);
        a3 = fmaf(xv.x, w0.w, a3); a3 = fmaf(xv.y, w1.w, a3);
        a3 = fmaf(xv.z, w2.w, a3); a3 = fmaf(xv.w, w3.w, a3);
    }
#pragma unroll
    for (int m = 32; m; m >>= 1) {
        a0 += __shfl_xor(a0, m, 64);
        a1 += __shfl_xor(a1, m, 64);
        a2 += __shfl_xor(a2, m, 64);
        a3 += __shfl_xor(a3, m, 64);
    }
    if (lane == 0) {
        float4 r; r.x = a0; r.y = a1; r.z = a2; r.w = a3;
        *(float4*)(Gl + (size_t)n * NG) = r;
    }
}

// ---------------------------------------------------------------------------
// Kernel 5: per-token gating finalize. Now also combines confp halves +
// sigmoid (conf_reduce kernel removed). Tie-break = lowest index.
// ---------------------------------------------------------------------------
__global__ __launch_bounds__(256) void finalize_kernel(
    const float* __restrict__ El, const float* __restrict__ Gl,
    const float* __restrict__ confp, const float* __restrict__ bgp,
    const float* __restrict__ bep, const float* __restrict__ prp,
    const float* __restrict__ bc2, float* __restrict__ out)
{
    const int n = blockIdx.x * 256 + threadIdx.x;

    float gl0 = Gl[(size_t)n * NG + 0] + bgp[0];
    float gl1 = Gl[(size_t)n * NG + 1] + bgp[1];
    float gl2 = Gl[(size_t)n * NG + 2] + bgp[2];
    float gl3 = Gl[(size_t)n * NG + 3] + bgp[3];
    float gm = fmaxf(fmaxf(gl0, gl1), fmaxf(gl2, gl3));
    float e0 = expf(gl0 - gm), e1 = expf(gl1 - gm);
    float e2 = expf(gl2 - gm), e3 = expf(gl3 - gm);
    float gs = e0 + e1 + e2 + e3;
    float gp0 = e0 / gs, gp1 = e1 / gs, gp2 = e2 / gs, gp3 = e3 / gs;

    int g0 = 0; float t0 = gp0;
    if (gp1 > t0) { t0 = gp1; g0 = 1; }
    if (gp2 > t0) { t0 = gp2; g0 = 2; }
    if (gp3 > t0) { t0 = gp3; g0 = 3; }
    int g1 = -1; float t1 = -1.0f;
    if (g0 != 0)              { t1 = gp0; g1 = 0; }
    if (g0 != 1 && gp1 > t1)  { t1 = gp1; g1 = 1; }
    if (g0 != 2 && gp2 > t1)  { t1 = gp2; g1 = 2; }
    if (g0 != 3 && gp3 > t1)  { t1 = gp3; g1 = 3; }

    const float cp = confp[n] + confp[(size_t)NTOK + n] + bc2[0];
    const float c = 1.0f / (1.0f + expf(-cp));
    const float uni = (1.0f - c) * (1.0f / 16.0f);

    int ci0, ci1, ci2, ci3;
    float cv0, cv1, cv2, cv3;

    auto proc = [&](int gid, float tp, int& ia, float& va, int& ib, float& vb) {
        const float* base = El + (size_t)n * NE + gid * EPG;
        const float* beb = bep + gid * EPG;
        const float* prb = prp + gid * EPG;
        float lv[16];
#pragma unroll
        for (int e = 0; e < 16; ++e) lv[e] = (base[e] + beb[e]) * prb[e];
        float m = lv[0];
#pragma unroll
        for (int e = 1; e < 16; ++e) m = fmaxf(m, lv[e]);
        float pe[16]; float s = 0.0f;
#pragma unroll
        for (int e = 0; e < 16; ++e) { pe[e] = expf(lv[e] - m); s += pe[e]; }
        const float cs = c / s;
        float bl[16];
#pragma unroll
        for (int e = 0; e < 16; ++e) bl[e] = fmaf(pe[e], cs, uni);
        int i0 = 0; float v0 = bl[0];
#pragma unroll
        for (int e = 1; e < 16; ++e) { if (bl[e] > v0) { v0 = bl[e]; i0 = e; } }
        int i1 = -1; float v1 = -1e30f;
#pragma unroll
        for (int e = 0; e < 16; ++e) {
            if (e != i0 && bl[e] > v1) { v1 = bl[e]; i1 = e; }
        }
        ia = gid * EPG + i0; va = v0 * tp;
        ib = gid * EPG + i1; vb = v1 * tp;
    };
    proc(g0, t0, ci0, cv0, ci1, cv1);
    proc(g1, t1, ci2, cv2, ci3, cv3);

    const float wsum = cv0 + cv1 + cv2 + cv3;
    const float winv = 1.0f / (wsum + 1e-9f);
    const float s0 = cv0 * winv, s1 = cv1 * winv;
    const float s2 = cv2 * winv, s3 = cv3 * winv;

    float bv = s0; int bi = ci0; int bslot = 0;
    if (s1 > bv || (s1 == bv && ci1 < bi)) { bv = s1; bi = ci1; bslot = 1; }
    if (s2 > bv || (s2 == bv && ci2 < bi)) { bv = s2; bi = ci2; bslot = 2; }
    if (s3 > bv || (s3 == bv && ci3 < bi)) { bv = s3; bi = ci3; bslot = 3; }
    float sv = -1.0f; int si = 1 << 30;
    if (bslot != 0 && (s0 > sv || (s0 == sv && ci0 < si))) { sv = s0; si = ci0; }
    if (bslot != 1 && (s1 > sv || (s1 == sv && ci1 < si))) { sv = s1; si = ci1; }
    if (bslot != 2 && (s2 > sv || (s2 == sv && ci2 < si))) { sv = s2; si = ci2; }
    if (bslot != 3 && (s3 > sv || (s3 == sv && ci3 < si))) { sv = s3; si = ci3; }

    float* d0 = out + (size_t)n * NE;
    float* d1 = out + (size_t)NTOK * NE + (size_t)n * NE;
#pragma unroll
    for (int q = 0; q < 16; ++q) {
        const int j = q * 4;
        float4 v;
        v.x = (j + 0 == bi) ? bv : ((j + 0 == si) ? sv : 0.0f);
        v.y = (j + 1 == bi) ? bv : ((j + 1 == si) ? sv : 0.0f);
        v.z = (j + 2 == bi) ? bv : ((j + 2 == si) ? sv : 0.0f);
        v.w = (j + 3 == bi) ? bv : ((j + 3 == si) ? sv : 0.0f);
        *(float4*)(d0 + j) = v;
        *(float4*)(d1 + j) = v;
    }
    if (n == 0) out[(size_t)2 * NTOK * NE] = 0.0f;   // aux_loss
}

// ---------------------------------------------------------------------------
extern "C" void kernel_launch(void* const* d_in, const int* in_sizes, int n_in,
                              void* d_out, int out_size, void* d_ws, size_t ws_size,
                              hipStream_t stream)
{
    const float* x    = (const float*)d_in[0];
    const float* Wg   = (const float*)d_in[1];
    const float* bg   = (const float*)d_in[2];
    const float* We   = (const float*)d_in[3];
    const float* be   = (const float*)d_in[4];
    const float* Wc1  = (const float*)d_in[5];
    const float* bc1  = (const float*)d_in[6];
    const float* Wc2  = (const float*)d_in[7];
    const float* bc2  = (const float*)d_in[8];
    const float* prio = (const float*)d_in[9];
    float* out = (float*)d_out;

    // ws layout (floats): confp[2*NTOK] | El[NTOK*64] | Gl[NTOK*4] | Elp[4*NTOK*64]
    // (h no longer materialized; ~21.4 MB total)
    float* confp = (float*)d_ws;
    float* El    = confp + (size_t)2 * NTOK;
    float* Gl    = El + (size_t)NTOK * NE;
    float* Elp   = Gl + (size_t)NTOK * NG;

    gemm_conf_kernel<<<dim3(NTOK / 64, 2), 512, 0, stream>>>(x, Wc1, bc1, Wc2, confp);
    gemm_experts_kernel<<<dim3(NTOK / 64, KSPLIT), 256, 0, stream>>>(x, We, Elp);
    reduce_el_kernel<<<(NTOK * NE / 4) / 256, 256, 0, stream>>>(Elp, El);
    gemv_gates_kernel<<<NTOK / 4, 256, 0, stream>>>(x, Wg, Gl);
    finalize_kernel<<<NTOK / 256, 256, 0, stream>>>(El, Gl, confp, bg, be, prio, bc2, out);
}